// Round 9
// baseline (206.317 us; speedup 1.0000x reference)
//
#include <hip/hip_runtime.h>

typedef __attribute__((ext_vector_type(8))) short short8;
typedef __attribute__((ext_vector_type(4))) float floatx4;
typedef __attribute__((ext_vector_type(2))) float floatx2;
typedef __attribute__((ext_vector_type(4))) float float4v;
typedef __attribute__((ext_vector_type(4))) unsigned short ushort4v;

static __device__ __forceinline__ unsigned short f2bf(float x) {
    unsigned int u = __builtin_bit_cast(unsigned int, x);
    unsigned int r = (u + 0x7FFFu + ((u >> 16) & 1u)) >> 16;
    return (unsigned short)r;
}

// One prep launch, three segments:
//   1) tables fp32->bf16 (float4-vectorized)
//   2) W1 [256k][128n] -> w1t [128n][256k] bf16
//   3) out[] = b2 (accumulation base for the atomicAdd epilogue)
__global__ void prep_all(const float* __restrict__ zd, const float* __restrict__ zs,
                         const float* __restrict__ W1, const float* __restrict__ b2,
                         int nd4, int ns4, int e4,
                         unsigned short* __restrict__ outd, unsigned short* __restrict__ outs,
                         unsigned short* __restrict__ w1t, float* __restrict__ out) {
    int i = blockIdx.x * 256 + threadIdx.x;
    int total4 = nd4 + ns4;
    if (i < total4) {
        const float* src; unsigned short* dst; int j;
        if (i < nd4) { src = zd; dst = outd; j = i; }
        else         { src = zs; dst = outs; j = i - nd4; }
        float4v v = *reinterpret_cast<const float4v*>(src + (size_t)j * 4);
        ushort4v o;
        o.x = f2bf(v.x); o.y = f2bf(v.y); o.z = f2bf(v.z); o.w = f2bf(v.w);
        *reinterpret_cast<ushort4v*>(dst + (size_t)j * 4) = o;
    } else if (i < total4 + 128 * 256) {
        int j = i - total4;
        int n = j >> 8;
        int k = j & 255;
        w1t[n * 256 + k] = f2bf(W1[k * 128 + n]);
    } else {
        int j = i - total4 - 128 * 256;
        if (j < e4) {
            float b = b2[0];
            float4v o = { b, b, b, b };
            *reinterpret_cast<float4v*>(out + (size_t)j * 4) = o;
        }
    }
}

// Barrier-free, LDS-free edge MLP.
// Wave pair (wh=0/1) covers one 32-edge tile: each wave computes 64 hidden
// (its wh half) x 32 edges x K=256, reduces layer-2 in-register + 2 shuffles,
// and atomicAdds its partial into out[] (pre-initialized to b2).
// B-fragments are loaded DIRECTLY from the bf16 tables (L1/L2-hot scatter):
//   lane: edge n = et*16 + (lane&15), k-chunk = s*32 + (lane>>4)*8
//   k < 128 -> z_drug[row[e]], else z_disease[col[e]]
__global__ __launch_bounds__(256, 2) void edge_mlp(
    const unsigned short* __restrict__ zd, const unsigned short* __restrict__ zs,
    const int* __restrict__ row, const int* __restrict__ col,
    const unsigned short* __restrict__ w1t,
    const float* __restrict__ b1, const float* __restrict__ w2,
    float* __restrict__ out, int rounds)
{
    const int tid  = threadIdx.x;
    const int lane = tid & 63;
    const int wave = tid >> 6;
    const int l15  = lane & 15;
    const int quad = lane >> 4;
    const int wh   = wave & 1;                       // hidden half
    const int whbase = wh * 64;
    const long wpair = (long)blockIdx.x * 2 + (wave >> 1);

    // ---- persistent W1 A-fragments for this wave's 64 hidden (128 regs) ----
    short8 wfrag[32];                                // [s*4 + mt]
    #pragma unroll
    for (int s = 0; s < 8; ++s)
        #pragma unroll
        for (int mt = 0; mt < 4; ++mt)
            wfrag[s * 4 + mt] = *reinterpret_cast<const short8*>(
                &w1t[(size_t)(whbase + mt * 16 + l15) * 256 + s * 32 + quad * 8]);

    // ---- persistent epilogue constants (32 regs) ----
    float4v b1v[4], w2v[4];
    #pragma unroll
    for (int mt = 0; mt < 4; ++mt) {
        b1v[mt] = *reinterpret_cast<const float4v*>(&b1[whbase + mt * 16 + quad * 4]);
        w2v[mt] = *reinterpret_cast<const float4v*>(&w2[whbase + mt * 16 + quad * 4]);
    }

    // ---- per-lane edge indices for the current tile ----
    const long eb0 = wpair * 1024;                   // 32 tiles x 32 edges, contiguous
    int idxc[4], idxn[4];
    idxc[0] = row[eb0 + l15];        idxc[1] = row[eb0 + 16 + l15];
    idxc[2] = col[eb0 + l15];        idxc[3] = col[eb0 + 16 + l15];

    floatx4 acc[2][4];                               // [et][mt]
    long ebp = 0;

    for (int k = 0; k < rounds; ++k) {
        const long eb = eb0 + (long)k * 32;

        // ---- issue B-frag loads, drug half (s=0..3) ----
        short8 efa[2][4];
        #pragma unroll
        for (int s = 0; s < 4; ++s)
            #pragma unroll
            for (int et = 0; et < 2; ++et)
                efa[et][s] = *reinterpret_cast<const short8*>(
                    zd + (size_t)idxc[et] * 128 + s * 32 + quad * 8);

        // ---- prefetch next tile's indices ----
        {
            long ebn = (k + 1 < rounds) ? eb + 32 : eb;
            idxn[0] = row[ebn + l15];  idxn[1] = row[ebn + 16 + l15];
            idxn[2] = col[ebn + l15];  idxn[3] = col[ebn + 16 + l15];
        }

        // ---- E1 for previous tile (packed fp32 math; overlaps load flight) ----
        if (k >= 1) {
            #pragma unroll
            for (int et = 0; et < 2; ++et) {
                floatx2 p01 = { 0.f, 0.f }, p23 = { 0.f, 0.f };
                #pragma unroll
                for (int mt = 0; mt < 4; ++mt) {
                    floatx2 h01 = { acc[et][mt][0], acc[et][mt][1] };
                    floatx2 h23 = { acc[et][mt][2], acc[et][mt][3] };
                    h01 += b1v[mt].xy;  h23 += b1v[mt].zw;
                    h01.x = h01.x > 0.f ? h01.x : 0.f;
                    h01.y = h01.y > 0.f ? h01.y : 0.f;
                    h23.x = h23.x > 0.f ? h23.x : 0.f;
                    h23.y = h23.y > 0.f ? h23.y : 0.f;
                    p01 += h01 * w2v[mt].xy;
                    p23 += h23 * w2v[mt].zw;
                }
                floatx2 ps = p01 + p23;
                float v = ps.x + ps.y;
                v += __shfl_xor(v, 16);
                v += __shfl_xor(v, 32);
                if (lane < 16)
                    atomicAdd(&out[ebp + et * 16 + l15], v);
            }
        }

        // ---- issue B-frag loads, disease half (s=4..7) ----
        short8 efb[2][4];
        #pragma unroll
        for (int s = 0; s < 4; ++s)
            #pragma unroll
            for (int et = 0; et < 2; ++et)
                efb[et][s] = *reinterpret_cast<const short8*>(
                    zs + (size_t)idxc[et + 2] * 128 + s * 32 + quad * 8);

        // ---- K loop: 64 MFMAs ----
        #pragma unroll
        for (int et = 0; et < 2; ++et)
            #pragma unroll
            for (int mt = 0; mt < 4; ++mt)
                acc[et][mt] = (floatx4)(0.0f);

        #pragma unroll
        for (int s = 0; s < 4; ++s)
            #pragma unroll
            for (int et = 0; et < 2; ++et)
                #pragma unroll
                for (int mt = 0; mt < 4; ++mt)
                    acc[et][mt] = __builtin_amdgcn_mfma_f32_16x16x32_bf16(
                        wfrag[s * 4 + mt], efa[et][s], acc[et][mt], 0, 0, 0);
        #pragma unroll
        for (int s = 0; s < 4; ++s)
            #pragma unroll
            for (int et = 0; et < 2; ++et)
                #pragma unroll
                for (int mt = 0; mt < 4; ++mt)
                    acc[et][mt] = __builtin_amdgcn_mfma_f32_16x16x32_bf16(
                        wfrag[(s + 4) * 4 + mt], efb[et][s], acc[et][mt], 0, 0, 0);

        idxc[0] = idxn[0]; idxc[1] = idxn[1]; idxc[2] = idxn[2]; idxc[3] = idxn[3];
        ebp = eb;
    }

    // ---- drain: E1 for the last tile ----
    #pragma unroll
    for (int et = 0; et < 2; ++et) {
        floatx2 p01 = { 0.f, 0.f }, p23 = { 0.f, 0.f };
        #pragma unroll
        for (int mt = 0; mt < 4; ++mt) {
            floatx2 h01 = { acc[et][mt][0], acc[et][mt][1] };
            floatx2 h23 = { acc[et][mt][2], acc[et][mt][3] };
            h01 += b1v[mt].xy;  h23 += b1v[mt].zw;
            h01.x = h01.x > 0.f ? h01.x : 0.f;
            h01.y = h01.y > 0.f ? h01.y : 0.f;
            h23.x = h23.x > 0.f ? h23.x : 0.f;
            h23.y = h23.y > 0.f ? h23.y : 0.f;
            p01 += h01 * w2v[mt].xy;
            p23 += h23 * w2v[mt].zw;
        }
        floatx2 ps = p01 + p23;
        float v = ps.x + ps.y;
        v += __shfl_xor(v, 16);
        v += __shfl_xor(v, 32);
        if (lane < 16)
            atomicAdd(&out[ebp + et * 16 + l15], v);
    }
}

extern "C" void kernel_launch(void* const* d_in, const int* in_sizes, int n_in,
                              void* d_out, int out_size, void* d_ws, size_t ws_size,
                              hipStream_t stream) {
    const float* zd = (const float*)d_in[0];
    const float* zs = (const float*)d_in[1];
    const int*   row = (const int*)d_in[2];
    const int*   col = (const int*)d_in[3];
    const float* W1 = (const float*)d_in[4];
    const float* b1 = (const float*)d_in[5];
    const float* w2 = (const float*)d_in[6];
    const float* b2 = (const float*)d_in[7];
    float* out = (float*)d_out;

    const int nd = in_sizes[0];   // 10000*128
    const int ns = in_sizes[1];   // 15000*128
    const int E  = in_sizes[2];   // 1048576

    unsigned short* zd_b = (unsigned short*)d_ws;
    unsigned short* zs_b = zd_b + nd;
    unsigned short* w1t  = zs_b + ns;   // 128*256 bf16

    const int total_jobs = (nd + ns) / 4 + 128 * 256 + E / 4;
    const int pgrid = (total_jobs + 255) / 256;
    hipLaunchKernelGGL(prep_all, dim3(pgrid), dim3(256), 0, stream,
                       zd, zs, W1, b2, nd / 4, ns / 4, E / 4, zd_b, zs_b, w1t, out);

    // 512 blocks x 256 thr = 2048 waves = 1024 wave-pairs; 32 tiles (of 32 edges) each
    const int nblocks = 512;
    const int rounds = E / (nblocks * 2 * 32);   // 32
    hipLaunchKernelGGL(edge_mlp, dim3(nblocks), dim3(256), 0, stream,
                       zd_b, zs_b, row, col, w1t, b1, w2, out, rounds);
}

// Round 10
// 191.369 us; speedup vs baseline: 1.0781x; 1.0781x over previous
//
#include <hip/hip_runtime.h>

typedef __attribute__((ext_vector_type(8))) short short8;
typedef __attribute__((ext_vector_type(16))) float floatx16;
typedef __attribute__((ext_vector_type(4))) float float4v;
typedef __attribute__((ext_vector_type(4))) unsigned short ushort4v;

#define TILE_M 64
#define TILE_SHORTS (TILE_M * 256)   // 16384 shorts = 32 KB per buffer (flat, swizzled)

static __device__ __forceinline__ unsigned short f2bf(float x) {
    unsigned int u = __builtin_bit_cast(unsigned int, x);
    unsigned int r = (u + 0x7FFFu + ((u >> 16) & 1u)) >> 16;
    return (unsigned short)r;
}

// async 16B global -> LDS (DMA, lands at lds_base + lane*16)
static __device__ __forceinline__ void gld16(const unsigned short* g, unsigned short* l) {
    __builtin_amdgcn_global_load_lds(
        (const __attribute__((address_space(1))) unsigned int*)g,
        (__attribute__((address_space(3))) unsigned int*)l, 16, 0, 0);
}

// One prep launch: tables fp32->bf16 (vectorized) + W1 [256k][128n] -> w1t [128n][256k] bf16
__global__ void prep_all(const float* __restrict__ zd, const float* __restrict__ zs,
                         const float* __restrict__ W1,
                         int nd4, int ns4,
                         unsigned short* __restrict__ outd, unsigned short* __restrict__ outs,
                         unsigned short* __restrict__ w1t) {
    int i = blockIdx.x * 256 + threadIdx.x;
    int total4 = nd4 + ns4;
    if (i < total4) {
        const float* src; unsigned short* dst; int j;
        if (i < nd4) { src = zd; dst = outd; j = i; }
        else         { src = zs; dst = outs; j = i - nd4; }
        float4v v = *reinterpret_cast<const float4v*>(src + (size_t)j * 4);
        ushort4v o;
        o.x = f2bf(v.x); o.y = f2bf(v.y); o.z = f2bf(v.z); o.w = f2bf(v.w);
        *reinterpret_cast<ushort4v*>(dst + (size_t)j * 4) = o;
    } else {
        int j = i - total4;
        if (j < 128 * 256) {
            int n = j >> 8;
            int k = j & 255;
            w1t[n * 256 + k] = f2bf(W1[k * 128 + n]);
        }
    }
}

// LDS tile layout (flat, DMA-compatible, XOR-swizzled): chunk slot c (16B) holds
// edge e = c>>5, physical chunk jx = c&31, storing logical k-chunk j = jx ^ (e&7).
//
// R8 pipeline, 32x32x16 MFMA edition. Per round r (ONE barrier per round):
//   barrier -> DMA(t_{r+1}) -> idx prefetch -> out(t_{r-2}) -> reduce(t_{r-1}) -> K(t_r)
// Wave split: wh = hidden half (64), we = edge half (32).
// MFMA 32x32x16: A = W1 (row=lane&31=hidden, k=(lane>>5)*8+j), B = edges
// (col=lane&31=edge, k=(lane>>5)*8+j), C: col=lane&31=edge, row=(reg&3)+8*(reg>>2)+4*(lane>>5).
// acc is initialized to b1 (folds the bias add); each lane owns ONE edge column ->
// epilogue needs a single shfl_xor(32).
__global__ __launch_bounds__(256, 2) void edge_mlp(
    const unsigned short* __restrict__ zd, const unsigned short* __restrict__ zs,
    const int* __restrict__ row, const int* __restrict__ col,
    const unsigned short* __restrict__ w1t,
    const float* __restrict__ b1, const float* __restrict__ w2,
    const float* __restrict__ b2, float* __restrict__ out, int ntiles)
{
    __shared__ unsigned short lds_a[2][TILE_SHORTS];  // 64 KB double buffer
    __shared__ float red[2][2][TILE_M];               // 1 KB, slot = tile_index & 1

    const int tid  = threadIdx.x;
    const int lane = tid & 63;
    const int wave = tid >> 6;
    const int wh   = wave >> 1;          // hidden half: [wh*64, wh*64+64)
    const int we   = wave & 1;           // edge half:   [we*32, we*32+32)
    const int l31  = lane & 31;
    const int h5   = lane >> 5;          // k-chunk half within MFMA operand
    const int whbase = wh * 64;

    // ---- persistent W1 A-fragments (128 VGPRs) ----
    // wfrag[s*2+mt]: hidden = whbase + mt*32 + l31, k = s*16 + h5*8 .. +7
    short8 wfrag[32];
    #pragma unroll
    for (int s = 0; s < 16; ++s)
        #pragma unroll
        for (int mt = 0; mt < 2; ++mt)
            wfrag[s * 2 + mt] = *reinterpret_cast<const short8*>(
                &w1t[(size_t)(whbase + mt * 32 + l31) * 256 + s * 16 + h5 * 8]);

    // ---- persistent b1/w2 in C-register order (32 VGPRs) ----
    // acc reg rr <-> hidden row (rr&3) + 8*(rr>>2) + 4*h5  => float4 group g = rr>>2
    float4v b1i[2][4], w2i[2][4];
    #pragma unroll
    for (int mt = 0; mt < 2; ++mt)
        #pragma unroll
        for (int g = 0; g < 4; ++g) {
            b1i[mt][g] = *reinterpret_cast<const float4v*>(&b1[whbase + mt * 32 + g * 8 + h5 * 4]);
            w2i[mt][g] = *reinterpret_cast<const float4v*>(&w2[whbase + mt * 32 + g * 8 + h5 * 4]);
        }
    const float b2v = b2[0];

    // ---- fixed staging geometry (identical to R8) ----
    const int e0 = tid >> 5;             // edges e0 + 8i
    const int jxw = tid & 31;            // physical chunk this thread fills
    const int jlog = jxw ^ (e0 & 7);     // logical k-chunk it fetches
    const unsigned short* tab = (jlog >= 16) ? zs : zd;
    const int* idxp = (jlog >= 16) ? col : row;
    const int koff = (jlog & 15) * 8;

    // reader geometry: edge col and its swizzle key
    const int ecol = we * 32 + l31;
    const int ek = ecol & 7;

    const int G = gridDim.x;
    const int R = ntiles / G;            // 16384/512 = 32, uniform
    const long t0 = blockIdx.x;

    // ---- prologue: DMA tile t0 into buf 0; prefetch indices for t0+G ----
    int nidx[8];
    #pragma unroll
    for (int i = 0; i < 8; ++i) nidx[i] = idxp[t0 * TILE_M + e0 + 8 * i];
    #pragma unroll
    for (int i = 0; i < 8; ++i)
        gld16(tab + (size_t)nidx[i] * 128 + koff, &lds_a[0][2048 * i + 512 * wave]);
    {
        long t1 = (R >= 2) ? (t0 + G) : t0;
        #pragma unroll
        for (int i = 0; i < 8; ++i) nidx[i] = idxp[t1 * TILE_M + e0 + 8 * i];
    }

    floatx16 acc[2];                     // [mt]

    for (int r = 0; r < R; ++r) {
        const long t = t0 + (long)r * G;

        // single barrier: drains DMA(t) into buf[r&1]; syncs red writes of round r-1
        __syncthreads();

        // (a) issue async DMA for tile t+G into the other buffer
        if (r + 1 < R) {
            #pragma unroll
            for (int i = 0; i < 8; ++i)
                gld16(tab + (size_t)nidx[i] * 128 + koff,
                      &lds_a[(r + 1) & 1][2048 * i + 512 * wave]);
        }
        // (b) prefetch indices for tile t+2G
        {
            long t2 = (r + 2 < R) ? (t0 + (long)(r + 2) * G) : t0;
            #pragma unroll
            for (int i = 0; i < 8; ++i) nidx[i] = idxp[t2 * TILE_M + e0 + 8 * i];
        }

        // (c) E2: out-write for tile t-2G (red slot r&1)
        if (r >= 2 && tid < TILE_M) {
            out[(t - 2 * G) * TILE_M + tid] =
                red[r & 1][0][tid] + red[r & 1][1][tid] + b2v;
        }

        // (d) E1: reduce acc of tile t-G into red slot (r-1)&1
        // acc already includes b1 (folded at init)
        if (r >= 1) {
            const int slot = (r - 1) & 1;
            float v = 0.f;
            #pragma unroll
            for (int mt = 0; mt < 2; ++mt)
                #pragma unroll
                for (int rr = 0; rr < 16; ++rr) {
                    float h = acc[mt][rr];
                    h = h > 0.f ? h : 0.f;
                    v += h * w2i[mt][rr >> 2][rr & 3];
                }
            v += __shfl_xor(v, 32);      // combine the two h5 row-halves
            if (lane < 32) red[slot][wh][ecol] = v;
        }

        // (e) K-loop: acc = b1 + W1half^T x Zhalf on buf[r&1]
        const unsigned short* buf = lds_a[r & 1];
        #pragma unroll
        for (int mt = 0; mt < 2; ++mt)
            #pragma unroll
            for (int g = 0; g < 4; ++g) {
                acc[mt][g * 4 + 0] = b1i[mt][g].x;
                acc[mt][g * 4 + 1] = b1i[mt][g].y;
                acc[mt][g * 4 + 2] = b1i[mt][g].z;
                acc[mt][g * 4 + 3] = b1i[mt][g].w;
            }

        #pragma unroll
        for (int s = 0; s < 16; ++s) {
            // B-frag: edge = ecol, logical chunk j = s*2 + h5, swizzled by ek
            short8 ef = *reinterpret_cast<const short8*>(
                &buf[ecol * 256 + ((s * 2 + h5) ^ ek) * 8]);
            #pragma unroll
            for (int mt = 0; mt < 2; ++mt)
                acc[mt] = __builtin_amdgcn_mfma_f32_32x32x16_bf16(
                    wfrag[s * 2 + mt], ef, acc[mt], 0, 0, 0);
        }
    }

    // ---- pipeline drain ----
    __syncthreads();                     // syncs red writes of round R-1 (E1 of tile R-2)
    if (R >= 2 && tid < TILE_M) {        // E2 for tile R-2
        long tt = t0 + (long)(R - 2) * G;
        out[tt * TILE_M + tid] = red[R & 1][0][tid] + red[R & 1][1][tid] + b2v;
    }
    {                                    // E1 for tile R-1
        const int slot = (R - 1) & 1;
        float v = 0.f;
        #pragma unroll
        for (int mt = 0; mt < 2; ++mt)
            #pragma unroll
            for (int rr = 0; rr < 16; ++rr) {
                float h = acc[mt][rr];
                h = h > 0.f ? h : 0.f;
                v += h * w2i[mt][rr >> 2][rr & 3];
            }
        v += __shfl_xor(v, 32);
        if (lane < 32) red[slot][wh][ecol] = v;
    }
    __syncthreads();
    if (tid < TILE_M) {                  // E2 for tile R-1
        long tt = t0 + (long)(R - 1) * G;
        out[tt * TILE_M + tid] = red[(R - 1) & 1][0][tid] + red[(R - 1) & 1][1][tid] + b2v;
    }
}

extern "C" void kernel_launch(void* const* d_in, const int* in_sizes, int n_in,
                              void* d_out, int out_size, void* d_ws, size_t ws_size,
                              hipStream_t stream) {
    const float* zd = (const float*)d_in[0];
    const float* zs = (const float*)d_in[1];
    const int*   row = (const int*)d_in[2];
    const int*   col = (const int*)d_in[3];
    const float* W1 = (const float*)d_in[4];
    const float* b1 = (const float*)d_in[5];
    const float* w2 = (const float*)d_in[6];
    const float* b2 = (const float*)d_in[7];
    float* out = (float*)d_out;

    const int nd = in_sizes[0];   // 10000*128
    const int ns = in_sizes[1];   // 15000*128
    const int E  = in_sizes[2];   // 1048576

    unsigned short* zd_b = (unsigned short*)d_ws;
    unsigned short* zs_b = zd_b + nd;
    unsigned short* w1t  = zs_b + ns;   // 128*256 bf16

    const int total_jobs = (nd + ns) / 4 + 128 * 256;
    const int pgrid = (total_jobs + 255) / 256;
    hipLaunchKernelGGL(prep_all, dim3(pgrid), dim3(256), 0, stream,
                       zd, zs, W1, nd / 4, ns / 4, zd_b, zs_b, w1t);

    const int ntiles = E / TILE_M;   // 16384
    const int nblocks = 512;         // 2 blocks/CU (LDS-limited), R = 32 rounds
    hipLaunchKernelGGL(edge_mlp, dim3(nblocks), dim3(256), 0, stream,
                       zd_b, zs_b, row, col, w1t, b1, w2, b2, out, ntiles);
}

// Round 11
// 148.387 us; speedup vs baseline: 1.3904x; 1.2897x over previous
//
#include <hip/hip_runtime.h>

typedef __attribute__((ext_vector_type(8))) short short8;
typedef __attribute__((ext_vector_type(4))) float floatx4;
typedef __attribute__((ext_vector_type(2))) float floatx2;
typedef __attribute__((ext_vector_type(4))) float float4v;
typedef __attribute__((ext_vector_type(4))) unsigned short ushort4v;

#define TILE_M 64
#define TILE_SHORTS (TILE_M * 256)   // 16384 shorts = 32 KB per buffer (flat, swizzled)
#define PREP_TAB_BLOCKS 1024

static __device__ __forceinline__ unsigned short f2bf(float x) {
    unsigned int u = __builtin_bit_cast(unsigned int, x);
    unsigned int r = (u + 0x7FFFu + ((u >> 16) & 1u)) >> 16;
    return (unsigned short)r;
}

// async 16B global -> LDS (DMA, lands at lds_base + lane*16)
static __device__ __forceinline__ void gld16(const unsigned short* g, unsigned short* l) {
    __builtin_amdgcn_global_load_lds(
        (const __attribute__((address_space(1))) unsigned int*)g,
        (__attribute__((address_space(3))) unsigned int*)l, 16, 0, 0);
}

// Bandwidth-shaped prep:
//   blocks [0, PREP_TAB_BLOCKS): tables fp32->bf16, grid-stride float4 (3-4
//     independent load/cvt/store per thread -> memory-level parallelism)
//   blocks [PREP_TAB_BLOCKS, +32): W1 [256k][128n] -> w1t [128n][256k] bf16
__global__ void prep_all(const float* __restrict__ zd, const float* __restrict__ zs,
                         const float* __restrict__ W1,
                         int nd4, int ns4,
                         unsigned short* __restrict__ outd, unsigned short* __restrict__ outs,
                         unsigned short* __restrict__ w1t) {
    const int b = blockIdx.x;
    if (b < PREP_TAB_BLOCKS) {
        const int S = PREP_TAB_BLOCKS * 256;
        const int total4 = nd4 + ns4;
        for (int i = b * 256 + threadIdx.x; i < total4; i += S) {
            const float* src; unsigned short* dst; int j;
            if (i < nd4) { src = zd; dst = outd; j = i; }
            else         { src = zs; dst = outs; j = i - nd4; }
            float4v v = *reinterpret_cast<const float4v*>(src + (size_t)j * 4);
            ushort4v o;
            o.x = f2bf(v.x); o.y = f2bf(v.y); o.z = f2bf(v.z); o.w = f2bf(v.w);
            *reinterpret_cast<ushort4v*>(dst + (size_t)j * 4) = o;
        }
    } else {
        const int j0 = (b - PREP_TAB_BLOCKS) * 256 + threadIdx.x;  // 0..8191
        #pragma unroll
        for (int u = 0; u < 4; ++u) {
            int j = j0 + u * 8192;          // 0..32767
            int n = j >> 8;
            int k = j & 255;
            w1t[n * 256 + k] = f2bf(W1[k * 128 + n]);
        }
    }
}

// LDS tile layout (flat, DMA-compatible, XOR-swizzled):
// chunk slot c (16B) holds edge e = c>>5, physical chunk jx = c&31, storing
// logical k-chunk j = jx ^ (e&7) of edge e's 256-short concat row.
//
// Software pipeline per round r (ONE barrier per round, nothing trapped before it
// except the K-loop itself):
//   barrier -> DMA(t_{r+1}) -> idx prefetch -> out(t_{r-2}) -> reduce(t_{r-1}) -> K(t_r)
// acc is initialized to b1 (bias folded into the MFMA C operand).
__global__ __launch_bounds__(256, 2) void edge_mlp(
    const unsigned short* __restrict__ zd, const unsigned short* __restrict__ zs,
    const int* __restrict__ row, const int* __restrict__ col,
    const unsigned short* __restrict__ w1t,
    const float* __restrict__ b1, const float* __restrict__ w2,
    const float* __restrict__ b2, float* __restrict__ out, int ntiles)
{
    __shared__ unsigned short lds_a[2][TILE_SHORTS];  // 64 KB double buffer
    __shared__ float red[2][2][TILE_M];               // 1 KB, slot = tile_index & 1

    const int tid  = threadIdx.x;
    const int lane = tid & 63;
    const int wave = tid >> 6;
    const int wh   = wave >> 1;          // hidden half: [wh*64, wh*64+64)
    const int we   = wave & 1;           // edge half:   [we*32, we*32+32)
    const int l15  = lane & 15;
    const int quad = lane >> 4;
    const int whbase = wh * 64;

    // ---- persistent W1 A-fragments from prepped w1t (128 regs, plain 16B loads) ----
    // A[m=hidden][k]: m = whbase + mt*16 + l15, k = s*32 + quad*8 + j
    short8 wfrag[32];                    // [s*4 + mt]
    #pragma unroll
    for (int s = 0; s < 8; ++s)
        #pragma unroll
        for (int mt = 0; mt < 4; ++mt)
            wfrag[s * 4 + mt] = *reinterpret_cast<const short8*>(
                &w1t[(size_t)(whbase + mt * 16 + l15) * 256 + s * 32 + quad * 8]);

    // ---- persistent epilogue constants (32 regs) ----
    // b1v[mt] matches acc[et][mt] C-layout exactly: hidden = whbase+mt*16+quad*4+rr
    float4v b1v[4], w2v[4];
    #pragma unroll
    for (int mt = 0; mt < 4; ++mt) {
        b1v[mt] = *reinterpret_cast<const float4v*>(&b1[whbase + mt * 16 + quad * 4]);
        w2v[mt] = *reinterpret_cast<const float4v*>(&w2[whbase + mt * 16 + quad * 4]);
    }
    const float b2v = b2[0];

    // ---- fixed staging geometry for this thread ----
    const int e0 = tid >> 5;             // edges e0 + 8i
    const int jxw = tid & 31;            // physical chunk this thread fills
    const int jlog = jxw ^ (e0 & 7);     // logical k-chunk it fetches
    const unsigned short* tab = (jlog >= 16) ? zs : zd;
    const int* idxp = (jlog >= 16) ? col : row;
    const int koff = (jlog & 15) * 8;

    // reader swizzle constants
    const int hb = (l15 >> 2) & 1;
    const int qx = quad ^ (l15 & 3);

    const int G = gridDim.x;
    const int R = ntiles / G;            // 16384/512 = 32, uniform
    const long t0 = blockIdx.x;

    // ---- prologue: DMA tile t0 into buf 0; prefetch indices for t0+G ----
    int nidx[8];
    #pragma unroll
    for (int i = 0; i < 8; ++i) nidx[i] = idxp[t0 * TILE_M + e0 + 8 * i];
    #pragma unroll
    for (int i = 0; i < 8; ++i)
        gld16(tab + (size_t)nidx[i] * 128 + koff, &lds_a[0][2048 * i + 512 * wave]);
    {
        long t1 = (R >= 2) ? (t0 + G) : t0;
        #pragma unroll
        for (int i = 0; i < 8; ++i) nidx[i] = idxp[t1 * TILE_M + e0 + 8 * i];
    }

    floatx4 acc[2][4];                   // [et][mt], includes b1 (folded at init)

    for (int r = 0; r < R; ++r) {
        const long t = t0 + (long)r * G;

        // single barrier: drains DMA(t) into buf[r&1]; syncs red writes of round r-1
        __syncthreads();

        // (a) issue async DMA for tile t+G into the other buffer — flies across
        // everything below plus the other block's work
        if (r + 1 < R) {
            #pragma unroll
            for (int i = 0; i < 8; ++i)
                gld16(tab + (size_t)nidx[i] * 128 + koff,
                      &lds_a[(r + 1) & 1][2048 * i + 512 * wave]);
        }
        // (b) prefetch indices for tile t+2G
        {
            long t2 = (r + 2 < R) ? (t0 + (long)(r + 2) * G) : t0;
            #pragma unroll
            for (int i = 0; i < 8; ++i) nidx[i] = idxp[t2 * TILE_M + e0 + 8 * i];
        }

        // (c) E2: out-write for tile t-2G (red slot r&1), spread over all 4 waves
        if (r >= 2 && lane < 16) {
            int eo = wave * 16 + l15;
            out[(t - 2 * G) * TILE_M + eo] =
                red[r & 1][0][eo] + red[r & 1][1][eo] + b2v;
        }

        // (d) E1: reduce acc of tile t-G into red slot (r-1)&1
        // b1 already folded into acc; packed float2 dot for the w2 reduction
        if (r >= 1) {
            const int slot = (r - 1) & 1;
            #pragma unroll
            for (int et = 0; et < 2; ++et) {
                floatx2 p = { 0.f, 0.f };
                #pragma unroll
                for (int mt = 0; mt < 4; ++mt) {
                    float4v h = acc[et][mt];
                    h.x = h.x > 0.f ? h.x : 0.f;
                    h.y = h.y > 0.f ? h.y : 0.f;
                    h.z = h.z > 0.f ? h.z : 0.f;
                    h.w = h.w > 0.f ? h.w : 0.f;
                    floatx2 hlo = { h.x, h.y }, hhi = { h.z, h.w };
                    floatx2 wlo = { w2v[mt].x, w2v[mt].y }, whi = { w2v[mt].z, w2v[mt].w };
                    p += hlo * wlo + hhi * whi;
                }
                float v = p.x + p.y;
                v += __shfl_xor(v, 16);
                v += __shfl_xor(v, 32);
                if (lane < 16) red[slot][wh][we * 32 + et * 16 + l15] = v;
            }
        }

        // (e) K-loop: acc = b1 + W1half^T x Zhalf on buf[r&1]
        const unsigned short* buf = lds_a[r & 1];
        #pragma unroll
        for (int et = 0; et < 2; ++et)
            #pragma unroll
            for (int mt = 0; mt < 4; ++mt)
                acc[et][mt] = b1v[mt];

        #pragma unroll
        for (int s = 0; s < 8; ++s) {
            const int sx = s ^ hb;
            short8 ef[2];
            #pragma unroll
            for (int et = 0; et < 2; ++et) {
                int e = we * 32 + et * 16 + l15;
                ef[et] = *reinterpret_cast<const short8*>(&buf[e * 256 + sx * 32 + qx * 8]);
            }
            #pragma unroll
            for (int et = 0; et < 2; ++et)
                #pragma unroll
                for (int mt = 0; mt < 4; ++mt)
                    acc[et][mt] = __builtin_amdgcn_mfma_f32_16x16x32_bf16(
                        wfrag[s * 4 + mt], ef[et], acc[et][mt], 0, 0, 0);
        }
    }

    // ---- pipeline drain ----
    __syncthreads();                     // syncs red writes of round R-1 (E1 of tile R-2)
    if (R >= 2 && lane < 16) {           // E2 for tile R-2 (slot R&1 == (R-2)&1)
        int eo = wave * 16 + l15;
        long tt = t0 + (long)(R - 2) * G;
        out[tt * TILE_M + eo] = red[R & 1][0][eo] + red[R & 1][1][eo] + b2v;
    }
    {                                    // E1 for tile R-1
        const int slot = (R - 1) & 1;
        #pragma unroll
        for (int et = 0; et < 2; ++et) {
            floatx2 p = { 0.f, 0.f };
            #pragma unroll
            for (int mt = 0; mt < 4; ++mt) {
                float4v h = acc[et][mt];
                h.x = h.x > 0.f ? h.x : 0.f;
                h.y = h.y > 0.f ? h.y : 0.f;
                h.z = h.z > 0.f ? h.z : 0.f;
                h.w = h.w > 0.f ? h.w : 0.f;
                floatx2 hlo = { h.x, h.y }, hhi = { h.z, h.w };
                floatx2 wlo = { w2v[mt].x, w2v[mt].y }, whi = { w2v[mt].z, w2v[mt].w };
                p += hlo * wlo + hhi * whi;
            }
            float v = p.x + p.y;
            v += __shfl_xor(v, 16);
            v += __shfl_xor(v, 32);
            if (lane < 16) red[slot][wh][we * 32 + et * 16 + l15] = v;
        }
    }
    __syncthreads();
    if (lane < 16) {                     // E2 for tile R-1
        int eo = wave * 16 + l15;
        long tt = t0 + (long)(R - 1) * G;
        out[tt * TILE_M + eo] = red[(R - 1) & 1][0][eo] + red[(R - 1) & 1][1][eo] + b2v;
    }
}

extern "C" void kernel_launch(void* const* d_in, const int* in_sizes, int n_in,
                              void* d_out, int out_size, void* d_ws, size_t ws_size,
                              hipStream_t stream) {
    const float* zd = (const float*)d_in[0];
    const float* zs = (const float*)d_in[1];
    const int*   row = (const int*)d_in[2];
    const int*   col = (const int*)d_in[3];
    const float* W1 = (const float*)d_in[4];
    const float* b1 = (const float*)d_in[5];
    const float* w2 = (const float*)d_in[6];
    const float* b2 = (const float*)d_in[7];
    float* out = (float*)d_out;

    const int nd = in_sizes[0];   // 10000*128
    const int ns = in_sizes[1];   // 15000*128
    const int E  = in_sizes[2];   // 1048576

    unsigned short* zd_b = (unsigned short*)d_ws;
    unsigned short* zs_b = zd_b + nd;
    unsigned short* w1t  = zs_b + ns;   // 128*256 bf16

    hipLaunchKernelGGL(prep_all, dim3(PREP_TAB_BLOCKS + 32), dim3(256), 0, stream,
                       zd, zs, W1, nd / 4, ns / 4, zd_b, zs_b, w1t);

    const int ntiles = E / TILE_M;   // 16384
    const int nblocks = 512;         // 2 blocks/CU (LDS-limited), R = 32 rounds
    hipLaunchKernelGGL(edge_mlp, dim3(nblocks), dim3(256), 0, stream,
                       zd_b, zs_b, row, col, w1t, b1, w2, b2, out, ntiles);
}